// Round 5
// baseline (925.984 us; speedup 1.0000x reference)
//
#include <hip/hip_runtime.h>

// ---------------------------------------------------------------------------
// NetGINE:
//   CSR-order build (by dst): hist + hierarchical scan + fused fill/perm
//   goff: binary search over sorted batch
//   bond_kernel: ebond = relu(attr@be1)@be2 via bf16 MFMA (dst-sorted bf16)
//   init_z:      z = (1+eps)*h  (zero-padded to RB)
//   agg_scatter: window-per-wave; m[64] reg array; segmented atomic row-adds
//   node_mfma_kernel: x = bn(relu(relu(z@m1)@m2)) via 2 chained MFMA GEMMs
//   pool + FC head
// ---------------------------------------------------------------------------

typedef __attribute__((ext_vector_type(8))) short short8v;
typedef __attribute__((ext_vector_type(4))) float float4v;

__device__ __forceinline__ unsigned short f2bf(float f) {  // RNE f32->bf16
  unsigned u = __float_as_uint(f);
  u += 0x7fff + ((u >> 16) & 1);
  return (unsigned short)(u >> 16);
}
__device__ __forceinline__ float bf2f(unsigned short s) {
  return __uint_as_float(((unsigned)s) << 16);
}
__device__ __forceinline__ float4v mfma16(short8v a, short8v b, float4v c) {
  return __builtin_amdgcn_mfma_f32_16x16x32_bf16(a, b, c, 0, 0, 0);
}

// ---------------- CSR build ----------------

__global__ void hist_kernel(const int* __restrict__ idx, int* __restrict__ cnt, int n) {
  int i = blockIdx.x * blockDim.x + threadIdx.x;
  int stride = gridDim.x * blockDim.x;
  for (; i < n; i += stride) atomicAdd(&cnt[idx[i]], 1);
}

// fused fill+perm: place edge i at its dst-sorted slot, writing all tables
__global__ void fill_perm_kernel(const int* __restrict__ srcs, const int* __restrict__ dsts,
                                 const float* __restrict__ eattr, int* __restrict__ cursor,
                                 int* __restrict__ src_s, int* __restrict__ dst_s,
                                 float4* __restrict__ attr_s, int n) {
  int i = blockIdx.x * blockDim.x + threadIdx.x;
  int stride = gridDim.x * blockDim.x;
  for (; i < n; i += stride) {
    int d = dsts[i];
    int p = atomicAdd(&cursor[d], 1);
    src_s[p] = srcs[i];
    dst_s[p] = d;
    attr_s[p] = make_float4(eattr[i * 3 + 0], eattr[i * 3 + 1], eattr[i * 3 + 2], 0.f);
  }
}

// --- hierarchical exclusive scan of counts[n] -> cursor ---
__global__ __launch_bounds__(256) void block_reduce_kernel(
    const int* __restrict__ cnt, int* __restrict__ bsum, int n) {
  __shared__ int s[256];
  int i = blockIdx.x * 256 + threadIdx.x;
  s[threadIdx.x] = (i < n) ? cnt[i] : 0;
  __syncthreads();
  for (int d = 128; d > 0; d >>= 1) {
    if (threadIdx.x < d) s[threadIdx.x] += s[threadIdx.x + d];
    __syncthreads();
  }
  if (threadIdx.x == 0) bsum[blockIdx.x] = s[0];
}

__global__ __launch_bounds__(256) void bsum_scan_kernel(int* __restrict__ bsum, int nb) {
  __shared__ int s[1024];
  for (int i = threadIdx.x; i < 1024; i += 256) s[i] = (i < nb) ? bsum[i] : 0;
  __syncthreads();
  if (threadIdx.x == 0) {
    int acc = 0;
    for (int i = 0; i < nb; i++) { int t = s[i]; s[i] = acc; acc += t; }
  }
  __syncthreads();
  for (int i = threadIdx.x; i < nb; i += 256) bsum[i] = s[i];
}

__global__ __launch_bounds__(256) void scan_apply_kernel(
    const int* __restrict__ cnt, const int* __restrict__ bsum,
    int* __restrict__ cursor, int n) {
  __shared__ int s[256];
  int b = blockIdx.x;
  int i = b * 256 + threadIdx.x;
  int v = (i < n) ? cnt[i] : 0;
  s[threadIdx.x] = v;
  __syncthreads();
  for (int d = 1; d < 256; d <<= 1) {
    int t = (threadIdx.x >= d) ? s[threadIdx.x - d] : 0;
    __syncthreads();
    s[threadIdx.x] += t;
    __syncthreads();
  }
  int excl = s[threadIdx.x] - v + bsum[b];
  if (i < n) cursor[i] = excl;
}

// --- graph boundaries from sorted batch ---
__global__ void boundary_kernel(const int* __restrict__ batch, int* __restrict__ goff,
                                int n, int G) {
  int g = blockIdx.x * blockDim.x + threadIdx.x;
  if (g > G) return;
  int lo = 0, hi = n;
  while (lo < hi) {
    int mid = (lo + hi) >> 1;
    if (batch[mid] < g) lo = mid + 1; else hi = mid;
  }
  goff[g] = lo;
}

// ---------------- bond encoder GEMM (MFMA) ----------------
template <int DE>
__global__ __launch_bounds__(256) void bond_kernel(
    const float4* __restrict__ attr_s, const float* __restrict__ be1,
    const float* __restrict__ be2, unsigned short* __restrict__ ebond, int E) {
  constexpr int KT = (DE + 31) / 32;   // 1 (DE=28) or 2 (DE=64)
  constexpr int NT = (DE + 15) / 16;   // 2 or 4
  constexpr int RB = KT * 32;          // ebond row width: 32 or 64
  constexpr int LROW = RB * 2 + 16;    // padded LDS row bytes, 16B-aligned
  __shared__ __attribute__((aligned(16))) char lds_all[4 * 16 * LROW];
  char* lds = lds_all + (threadIdx.x >> 6) * (16 * LROW);
  int lane = threadIdx.x & 63;
  int nc = lane & 15, kr = (lane >> 4) * 8, rr = (lane >> 4) * 4;
  int gw = (blockIdx.x * blockDim.x + threadIdx.x) >> 6;
  int nw = (gridDim.x * blockDim.x) >> 6;

  float b10 = 0.f, b11 = 0.f, b12 = 0.f;
  if (lane < DE) { b10 = be1[lane]; b11 = be1[DE + lane]; b12 = be1[2 * DE + lane]; }

  short8v bfrag[NT][KT];
#pragma unroll
  for (int nt = 0; nt < NT; nt++)
#pragma unroll
    for (int kt = 0; kt < KT; kt++) {
      short8v f;
#pragma unroll
      for (int j = 0; j < 8; j++) {
        int k = kt * 32 + kr + j, n = nt * 16 + nc;
        float w = (k < DE && n < DE) ? be2[k * DE + n] : 0.f;
        f[j] = (short)f2bf(w);
      }
      bfrag[nt][kt] = f;
    }

  int ntiles = (E + 15) >> 4;
  for (int tile = gw; tile < ntiles; tile += nw) {
    int j0 = __builtin_amdgcn_readfirstlane(tile) << 4;
#pragma unroll
    for (int e = 0; e < 16; e++) {
      int j = j0 + e;
      float t = 0.f;
      if (j < E) {
        float4 a = attr_s[j];  // wave-uniform -> s_load
        t = fmaxf(fmaf(a.x, b10, fmaf(a.y, b11, a.z * b12)), 0.f);
      }
      *(unsigned short*)(lds + e * LROW + lane * 2) = f2bf(t);
    }
    asm volatile("" ::: "memory");
    short8v af[KT];
#pragma unroll
    for (int kt = 0; kt < KT; kt++)
      af[kt] = *(const short8v*)(lds + (lane & 15) * LROW + (lane >> 4) * 16 + kt * 64);
    float4v acc[NT];
#pragma unroll
    for (int nt = 0; nt < NT; nt++) {
      acc[nt] = (float4v){0.f, 0.f, 0.f, 0.f};
#pragma unroll
      for (int kt = 0; kt < KT; kt++) acc[nt] = mfma16(af[kt], bfrag[nt][kt], acc[nt]);
    }
#pragma unroll
    for (int nt = 0; nt < NT; nt++)
#pragma unroll
      for (int r = 0; r < 4; r++) {
        int row = j0 + rr + r;
        if (row < E) ebond[(size_t)row * RB + nt * 16 + nc] = f2bf(acc[nt][r]);
      }
    asm volatile("" ::: "memory");
  }
}

// ---------------- z init: z = (1+eps)*h, zero-padded to RB ----------------
template <int DH, int RB>
__global__ __launch_bounds__(256) void init_z_kernel(const float* __restrict__ h,
                                                     const float* __restrict__ epsp,
                                                     float* __restrict__ z, int n_nodes) {
  int i = blockIdx.x * blockDim.x + threadIdx.x;
  if (i >= n_nodes * RB) return;
  int v = i / RB, c = i % RB;
  float val = 0.f;
  if (DH == RB || c < DH) val = (1.f + epsp[0]) * h[(size_t)v * DH + c];
  z[i] = val;
}

// ---------------- edge aggregation: window-per-wave scatter ----------------
// Each wave owns edges [wid*64, wid*64+64) of the dst-sorted list.
// Phase A: m[e] = relu(h[src_e] + ebond_e)  (64 independent gathers in flight)
// Phase B: segmented reduce over sorted dsts, one atomic row-add per segment.
template <int DH, int RB>
__global__ __launch_bounds__(256) void agg_scatter_kernel(
    const float* __restrict__ h, const unsigned short* __restrict__ eb,
    const int* __restrict__ src_s, const int* __restrict__ dst_s,
    float* __restrict__ z, int E) {
  int wid = (blockIdx.x * blockDim.x + threadIdx.x) >> 6;
  int lane = threadIdx.x & 63;
  int base = wid << 6;
  if (base >= E) return;
  int nvalid = min(64, E - base);
  int jj = min(base + lane, E - 1);
  int dv = dst_s[jj];
  int sv = src_s[jj];
  const bool hl = (DH == 64) || (lane < DH);
  const bool el = (RB == 64) || (lane < RB);

  float m[64];
#pragma unroll
  for (int e = 0; e < 64; e++) {
    if (e < nvalid) {
      int s = __builtin_amdgcn_readlane(sv, e);
      float ebv = el ? bf2f(eb[(size_t)(base + e) * RB + lane]) : 0.f;
      float hs = hl ? h[(size_t)s * DH + lane] : 0.f;
      m[e] = fmaxf(hs + ebv, 0.f);
    }
  }

  float acc = 0.f;
  int cur = __builtin_amdgcn_readfirstlane(dv);
#pragma unroll
  for (int e = 0; e < 64; e++) {
    if (e < nvalid) {
      int d = __builtin_amdgcn_readlane(dv, e);
      if (d != cur) {
        if (el) atomicAdd(&z[(size_t)cur * RB + lane], acc);
        acc = 0.f;
        cur = d;
      }
      acc += m[e];
    }
  }
  if (el) atomicAdd(&z[(size_t)cur * RB + lane], acc);
}

// ---------------- node MLP + relu + BN (MFMA) ----------------
template <int DIN>
__global__ __launch_bounds__(256) void node_mfma_kernel(
    const float* __restrict__ z, const float* __restrict__ m1,
    const float* __restrict__ m2, const float* __restrict__ bng,
    const float* __restrict__ bnb, const float* __restrict__ bnm,
    const float* __restrict__ bnv, float* __restrict__ xout, int n_nodes) {
  constexpr int KT = (DIN + 31) / 32;   // 1 or 2
  constexpr int NTH = (DIN + 15) / 16;  // 2 or 4
  constexpr int ZR = KT * 32;
  constexpr int LROW = ZR * 2 + 16;
  __shared__ __attribute__((aligned(16))) char lds_all[8 * 16 * LROW];
  char* zl = lds_all + (threadIdx.x >> 6) * (16 * LROW);
  char* yl = lds_all + (4 + (threadIdx.x >> 6)) * (16 * LROW);
  int lane = threadIdx.x & 63;
  int nc = lane & 15, kr = (lane >> 4) * 8, rr = (lane >> 4) * 4;
  int gw = (blockIdx.x * blockDim.x + threadIdx.x) >> 6;
  int nw = (gridDim.x * blockDim.x) >> 6;

  short8v m1f[NTH][KT], m2f[4][KT];
#pragma unroll
  for (int nt = 0; nt < NTH; nt++)
#pragma unroll
    for (int kt = 0; kt < KT; kt++) {
      short8v f;
#pragma unroll
      for (int j = 0; j < 8; j++) {
        int k = kt * 32 + kr + j, n = nt * 16 + nc;
        float w = (k < DIN && n < DIN) ? m1[k * DIN + n] : 0.f;
        f[j] = (short)f2bf(w);
      }
      m1f[nt][kt] = f;
    }
#pragma unroll
  for (int nt = 0; nt < 4; nt++)
#pragma unroll
    for (int kt = 0; kt < KT; kt++) {
      short8v f;
#pragma unroll
      for (int j = 0; j < 8; j++) {
        int k = kt * 32 + kr + j, n = nt * 16 + nc;
        float w = (k < DIN) ? m2[k * 64 + n] : 0.f;
        f[j] = (short)f2bf(w);
      }
      m2f[nt][kt] = f;
    }
  float scv[4], shv[4];
#pragma unroll
  for (int nt = 0; nt < 4; nt++) {
    int f = nt * 16 + nc;
    float sc = bng[f] * rsqrtf(bnv[f] + 1e-5f);
    scv[nt] = sc;
    shv[nt] = bnb[f] - bnm[f] * sc;
  }

  int ntiles = (n_nodes + 15) >> 4;
  for (int tile = gw; tile < ntiles; tile += nw) {
    int v0 = __builtin_amdgcn_readfirstlane(tile) << 4;
#pragma unroll
    for (int r = 0; r < 16; r++) {
      int v = v0 + r;
      float zv = (v < n_nodes && lane < ZR) ? z[(size_t)v * ZR + lane] : 0.f;
      if (lane < ZR) *(unsigned short*)(zl + r * LROW + lane * 2) = f2bf(zv);
    }
    asm volatile("" ::: "memory");
    short8v af[KT];
#pragma unroll
    for (int kt = 0; kt < KT; kt++)
      af[kt] = *(const short8v*)(zl + (lane & 15) * LROW + (lane >> 4) * 16 + kt * 64);
    float4v acch[NTH];
#pragma unroll
    for (int nt = 0; nt < NTH; nt++) {
      acch[nt] = (float4v){0.f, 0.f, 0.f, 0.f};
#pragma unroll
      for (int kt = 0; kt < KT; kt++) acch[nt] = mfma16(af[kt], m1f[nt][kt], acch[nt]);
    }
#pragma unroll
    for (int nt = 0; nt < NTH; nt++)
#pragma unroll
      for (int r = 0; r < 4; r++)
        *(unsigned short*)(yl + (rr + r) * LROW + (nt * 16 + nc) * 2) =
            f2bf(fmaxf(acch[nt][r], 0.f));
    asm volatile("" ::: "memory");
    short8v af2[KT];
#pragma unroll
    for (int kt = 0; kt < KT; kt++)
      af2[kt] = *(const short8v*)(yl + (lane & 15) * LROW + (lane >> 4) * 16 + kt * 64);
    float4v acco[4];
#pragma unroll
    for (int nt = 0; nt < 4; nt++) {
      acco[nt] = (float4v){0.f, 0.f, 0.f, 0.f};
#pragma unroll
      for (int kt = 0; kt < KT; kt++) acco[nt] = mfma16(af2[kt], m2f[nt][kt], acco[nt]);
    }
#pragma unroll
    for (int nt = 0; nt < 4; nt++)
#pragma unroll
      for (int r = 0; r < 4; r++) {
        int v = v0 + rr + r;
        if (v < n_nodes)
          xout[(size_t)v * 64 + nt * 16 + nc] =
              fmaf(fmaxf(acco[nt][r], 0.f), scv[nt], shv[nt]);
      }
    asm volatile("" ::: "memory");
  }
}

// ---------------- graph mean-pool of concat(x1..x4) ----------------
__global__ __launch_bounds__(256) void pool_kernel(
    const float* __restrict__ x1, const float* __restrict__ x2,
    const float* __restrict__ x3, const float* __restrict__ x4,
    const int* __restrict__ goff, float* __restrict__ pooled, int G) {
  int g = blockIdx.x;
  int c = threadIdx.x;
  int sel = c >> 6, f = c & 63;
  const float* x = (sel == 0) ? x1 : (sel == 1) ? x2 : (sel == 2) ? x3 : x4;
  int s = goff[g], e = goff[g + 1];
  float acc = 0.f;
  for (int v = s; v < e; v++) acc += x[(size_t)v * 64 + f];
  float cnt = (float)(e - s);
  pooled[g * 256 + c] = acc / fmaxf(cnt, 1.0f);
}

// ---------------- FC head ----------------
__global__ __launch_bounds__(64) void head_kernel(
    const float* __restrict__ pooled,
    const float* __restrict__ w1, const float* __restrict__ b1,
    const float* __restrict__ w2, const float* __restrict__ b2,
    const float* __restrict__ w3, const float* __restrict__ b3,
    const float* __restrict__ w4, const float* __restrict__ b4,
    float* __restrict__ out, int G) {
  int g = blockIdx.x;
  int lane = threadIdx.x;
  __shared__ float sh[256];
  for (int i = lane; i < 256; i += 64) sh[i] = pooled[g * 256 + i];
  __syncthreads();
  float h1 = b1[lane];
#pragma unroll 8
  for (int i = 0; i < 256; i++) h1 = fmaf(sh[i], w1[i * 64 + lane], h1);
  h1 = fmaxf(h1, 0.f);
  __syncthreads();
  sh[lane] = h1;
  __syncthreads();
  float h2 = b2[lane];
#pragma unroll
  for (int i = 0; i < 64; i++) h2 = fmaf(sh[i], w2[i * 64 + lane], h2);
  h2 = fmaxf(h2, 0.f);
  __syncthreads();
  sh[lane] = h2;
  __syncthreads();
  float h3 = b3[lane];
#pragma unroll
  for (int i = 0; i < 64; i++) h3 = fmaf(sh[i], w3[i * 64 + lane], h3);
  h3 = fmaxf(h3, 0.f);
  float p = h3 * w4[lane];
  for (int d = 32; d > 0; d >>= 1) p += __shfl_down(p, d);
  if (lane == 0) out[g] = p + b4[0];
}

// ---------------------------------------------------------------------------

extern "C" void kernel_launch(void* const* d_in, const int* in_sizes, int n_in,
                              void* d_out, int out_size, void* d_ws, size_t ws_size,
                              hipStream_t stream) {
  const float* x      = (const float*)d_in[0];
  const float* eattr  = (const float*)d_in[1];
  const float* c1_be1 = (const float*)d_in[2];
  const float* c1_be2 = (const float*)d_in[3];
  const float* c1_m1  = (const float*)d_in[4];
  const float* c1_m2  = (const float*)d_in[5];
  const float* c1_eps = (const float*)d_in[6];
  const float* c2_be1 = (const float*)d_in[7];
  const float* c2_be2 = (const float*)d_in[8];
  const float* c2_m1  = (const float*)d_in[9];
  const float* c2_m2  = (const float*)d_in[10];
  const float* c2_eps = (const float*)d_in[11];
  const float* c3_be1 = (const float*)d_in[12];
  const float* c3_be2 = (const float*)d_in[13];
  const float* c3_m1  = (const float*)d_in[14];
  const float* c3_m2  = (const float*)d_in[15];
  const float* c3_eps = (const float*)d_in[16];
  const float* bn_g[4] = {(const float*)d_in[17], (const float*)d_in[21],
                          (const float*)d_in[25], (const float*)d_in[29]};
  const float* bn_b[4] = {(const float*)d_in[18], (const float*)d_in[22],
                          (const float*)d_in[26], (const float*)d_in[30]};
  const float* bn_m[4] = {(const float*)d_in[19], (const float*)d_in[23],
                          (const float*)d_in[27], (const float*)d_in[31]};
  const float* bn_v[4] = {(const float*)d_in[20], (const float*)d_in[24],
                          (const float*)d_in[28], (const float*)d_in[32]};
  const float* fc1_w = (const float*)d_in[33];
  const float* fc1_b = (const float*)d_in[34];
  const float* fc2_w = (const float*)d_in[35];
  const float* fc2_b = (const float*)d_in[36];
  const float* fc3_w = (const float*)d_in[37];
  const float* fc3_b = (const float*)d_in[38];
  const float* fc4_w = (const float*)d_in[39];
  const float* fc4_b = (const float*)d_in[40];
  const int* eidx  = (const int*)d_in[41];
  const int* batch = (const int*)d_in[42];

  const int N = in_sizes[0] / 28;
  const int E = in_sizes[1] / 3;
  const int G = out_size;
  const int* src = eidx;
  const int* dst = eidx + E;
  float* outf = (float*)d_out;

  char* p = (char*)d_ws;
  auto alloc = [&](size_t bytes) {
    char* r = p;
    p += (bytes + 255) & ~(size_t)255;
    return r;
  };
  const int NBLK = (N + 255) / 256;
  int* counts   = (int*)alloc((size_t)N * 4);
  int* cursor   = (int*)alloc((size_t)N * 4);
  int* bsum     = (int*)alloc((size_t)NBLK * 4);
  int* goff     = (int*)alloc((size_t)(G + 1) * 4);
  int* src_s    = (int*)alloc((size_t)E * 4);
  int* dst_s    = (int*)alloc((size_t)E * 4);
  float4* attr_s = (float4*)alloc((size_t)E * 16);
  unsigned short* ebond = (unsigned short*)alloc((size_t)E * 64 * 2);  // reused per layer
  float* zbuf   = (float*)alloc((size_t)N * 64 * 4);
  float* x1     = (float*)alloc((size_t)N * 64 * 4);
  float* x2     = (float*)alloc((size_t)N * 64 * 4);
  float* x3     = (float*)alloc((size_t)N * 64 * 4);
  float* x4     = (float*)alloc((size_t)N * 64 * 4);
  float* pooled = (float*)alloc((size_t)G * 256 * 4);
  (void)ws_size; (void)n_in;

  hipMemsetAsync(counts, 0, (size_t)N * 4, stream);
  hist_kernel<<<1024, 256, 0, stream>>>(dst, counts, E);
  boundary_kernel<<<(G + 128) / 128, 128, 0, stream>>>(batch, goff, N, G);
  block_reduce_kernel<<<NBLK, 256, 0, stream>>>(counts, bsum, N);
  bsum_scan_kernel<<<1, 256, 0, stream>>>(bsum, NBLK);
  scan_apply_kernel<<<NBLK, 256, 0, stream>>>(counts, bsum, cursor, N);
  fill_perm_kernel<<<1024, 256, 0, stream>>>(src, dst, eattr, cursor, src_s, dst_s,
                                             attr_s, E);

  const int AGG_BLK = ((E + 63) / 64 * 64 + 255) / 256;  // one 64-edge window per wave
  dim3 blk(256);
  // layer 1
  bond_kernel<28><<<1024, blk, 0, stream>>>(attr_s, c1_be1, c1_be2, ebond, E);
  init_z_kernel<28, 32><<<(N * 32 + 255) / 256, blk, 0, stream>>>(x, c1_eps, zbuf, N);
  agg_scatter_kernel<28, 32><<<AGG_BLK, blk, 0, stream>>>(x, ebond, src_s, dst_s, zbuf, E);
  node_mfma_kernel<28><<<1024, blk, 0, stream>>>(zbuf, c1_m1, c1_m2, bn_g[0], bn_b[0],
                                                 bn_m[0], bn_v[0], x1, N);
  // layer 2
  bond_kernel<64><<<1024, blk, 0, stream>>>(attr_s, c2_be1, c2_be2, ebond, E);
  init_z_kernel<64, 64><<<(N * 64 + 255) / 256, blk, 0, stream>>>(x1, c2_eps, zbuf, N);
  agg_scatter_kernel<64, 64><<<AGG_BLK, blk, 0, stream>>>(x1, ebond, src_s, dst_s, zbuf, E);
  node_mfma_kernel<64><<<1024, blk, 0, stream>>>(zbuf, c2_m1, c2_m2, bn_g[1], bn_b[1],
                                                 bn_m[1], bn_v[1], x2, N);
  // layer 3
  bond_kernel<64><<<1024, blk, 0, stream>>>(attr_s, c3_be1, c3_be2, ebond, E);
  init_z_kernel<64, 64><<<(N * 64 + 255) / 256, blk, 0, stream>>>(x2, c3_eps, zbuf, N);
  agg_scatter_kernel<64, 64><<<AGG_BLK, blk, 0, stream>>>(x2, ebond, src_s, dst_s, zbuf, E);
  node_mfma_kernel<64><<<1024, blk, 0, stream>>>(zbuf, c3_m1, c3_m2, bn_g[2], bn_b[2],
                                                 bn_m[2], bn_v[2], x3, N);
  // layer 4 (conv3 weights reused -> ebond already holds c3 bond encodings)
  init_z_kernel<64, 64><<<(N * 64 + 255) / 256, blk, 0, stream>>>(x3, c3_eps, zbuf, N);
  agg_scatter_kernel<64, 64><<<AGG_BLK, blk, 0, stream>>>(x3, ebond, src_s, dst_s, zbuf, E);
  node_mfma_kernel<64><<<1024, blk, 0, stream>>>(zbuf, c3_m1, c3_m2, bn_g[3], bn_b[3],
                                                 bn_m[3], bn_v[3], x4, N);

  pool_kernel<<<G, blk, 0, stream>>>(x1, x2, x3, x4, goff, pooled, G);
  head_kernel<<<G, 64, 0, stream>>>(pooled, fc1_w, fc1_b, fc2_w, fc2_b, fc3_w,
                                    fc3_b, fc4_w, fc4_b, outf, G);
}

// Round 7
// 619.522 us; speedup vs baseline: 1.4947x; 1.4947x over previous
//
#include <hip/hip_runtime.h>

// ---------------------------------------------------------------------------
// NetGINE:
//   prep_kernel: weights -> frag-layout bf16 buffers (one launch, 12 blocks)
//   CSR build (by dst): hist + hierarchical scan + fused fill/perm
//   goff: binary search over sorted batch
//   bond_kernel: ebond = relu(attr@be1)@be2, LDS-free MFMA (per-lane t calc)
//   agg_kernel:  z[v] = (1+eps)h[v] + sum relu(h[src] + ebond)  (CSR gather,
//                8-wide batched unroll for gather ILP)
//   node_mfma_kernel: x = bn(relu(relu(z@m1)@m2)); direct-global A-frag,
//                LDS only for y transpose; frag weights from prep buffers
//   pool + FC head
// ---------------------------------------------------------------------------

typedef __attribute__((ext_vector_type(8))) short short8v;
typedef __attribute__((ext_vector_type(4))) float float4v;

__device__ __forceinline__ unsigned short f2bf(float f) {  // RNE f32->bf16
  unsigned u = __float_as_uint(f);
  u += 0x7fff + ((u >> 16) & 1);
  return (unsigned short)(u >> 16);
}
__device__ __forceinline__ float bf2f(unsigned short s) {
  return __uint_as_float(((unsigned)s) << 16);
}
__device__ __forceinline__ float4v mfma16(short8v a, short8v b, float4v c) {
  return __builtin_amdgcn_mfma_f32_16x16x32_bf16(a, b, c, 0, 0, 0);
}

// ---------------- weight prep: frag-layout bf16 buffers ----------------
// FB slot (4096 ushorts each): frag fi=nt*KT+kt, lane l, j:
//   out[(fi*64+l)*8+j] = bf16(W[(kt*32+(l>>4)*8+j)*ldw + nt*16+(l&15)])
// B1P slot (64*48 floats): out[l*48 + c*16 + kt*8 + j] = be1[c*DE + k]
__global__ __launch_bounds__(256) void prep_kernel(
    const float* c1be2, const float* c2be2, const float* c3be2,
    const float* c1m1, const float* c2m1, const float* c3m1,
    const float* c1m2, const float* c2m2, const float* c3m2,
    const float* c1be1, const float* c2be1, const float* c3be1,
    unsigned short* FB, float* B1P) {
  int job = blockIdx.x;
  if (job < 9) {
    const float* W = nullptr; int ldw = 0, kmax = 0, nmax = 0, NT = 0, KT = 0;
    switch (job) {
      case 0: W = c1be2; ldw = 28; kmax = 28; nmax = 28; NT = 2; KT = 1; break;
      case 1: W = c2be2; ldw = 64; kmax = 64; nmax = 64; NT = 4; KT = 2; break;
      case 2: W = c3be2; ldw = 64; kmax = 64; nmax = 64; NT = 4; KT = 2; break;
      case 3: W = c1m1;  ldw = 28; kmax = 28; nmax = 28; NT = 2; KT = 1; break;
      case 4: W = c2m1;  ldw = 64; kmax = 64; nmax = 64; NT = 4; KT = 2; break;
      case 5: W = c3m1;  ldw = 64; kmax = 64; nmax = 64; NT = 4; KT = 2; break;
      case 6: W = c1m2;  ldw = 64; kmax = 28; nmax = 64; NT = 4; KT = 1; break;
      case 7: W = c2m2;  ldw = 64; kmax = 64; nmax = 64; NT = 4; KT = 2; break;
      case 8: W = c3m2;  ldw = 64; kmax = 64; nmax = 64; NT = 4; KT = 2; break;
    }
    unsigned short* out = FB + (size_t)job * 4096;
    int total = NT * KT * 512;
    for (int i = threadIdx.x; i < total; i += 256) {
      int fi = i >> 9, l = (i >> 3) & 63, j = i & 7;
      int kt = fi % KT, nt = fi / KT;
      int k = kt * 32 + (l >> 4) * 8 + j;
      int n = nt * 16 + (l & 15);
      float w = (k < kmax && n < nmax) ? W[k * ldw + n] : 0.f;
      out[i] = f2bf(w);
    }
  } else {
    int b = job - 9;
    const float* be1 = (b == 0) ? c1be1 : (b == 1) ? c2be1 : c3be1;
    int DE = (b == 0) ? 28 : 64;
    float* out = B1P + (size_t)b * (64 * 48);
    for (int i = threadIdx.x; i < 64 * 48; i += 256) {
      int l = i / 48, r = i % 48;
      int c = r / 16, kk = r % 16;
      int kt = kk >> 3, j = kk & 7;
      int k = kt * 32 + ((l >> 4) & 3) * 8 + j;
      out[i] = (k < DE) ? be1[c * DE + k] : 0.f;
    }
  }
}

// ---------------- CSR build ----------------

__global__ void hist_kernel(const int* __restrict__ idx, int* __restrict__ cnt, int n) {
  int i = blockIdx.x * blockDim.x + threadIdx.x;
  int stride = gridDim.x * blockDim.x;
  for (; i < n; i += stride) atomicAdd(&cnt[idx[i]], 1);
}

__global__ void fill_perm_kernel(const int* __restrict__ srcs, const int* __restrict__ dsts,
                                 const float* __restrict__ eattr, int* __restrict__ cursor,
                                 int* __restrict__ src_s, float4* __restrict__ attr_s,
                                 int n) {
  int i = blockIdx.x * blockDim.x + threadIdx.x;
  int stride = gridDim.x * blockDim.x;
  for (; i < n; i += stride) {
    int d = dsts[i];
    int p = atomicAdd(&cursor[d], 1);
    src_s[p] = srcs[i];
    attr_s[p] = make_float4(eattr[i * 3 + 0], eattr[i * 3 + 1], eattr[i * 3 + 2], 0.f);
  }
}

__global__ __launch_bounds__(256) void block_reduce_kernel(
    const int* __restrict__ cnt, int* __restrict__ bsum, int n) {
  __shared__ int s[256];
  int i = blockIdx.x * 256 + threadIdx.x;
  s[threadIdx.x] = (i < n) ? cnt[i] : 0;
  __syncthreads();
  for (int d = 128; d > 0; d >>= 1) {
    if (threadIdx.x < d) s[threadIdx.x] += s[threadIdx.x + d];
    __syncthreads();
  }
  if (threadIdx.x == 0) bsum[blockIdx.x] = s[0];
}

__global__ __launch_bounds__(256) void bsum_scan_kernel(int* __restrict__ bsum, int nb) {
  __shared__ int s[1024];
  for (int i = threadIdx.x; i < 1024; i += 256) s[i] = (i < nb) ? bsum[i] : 0;
  __syncthreads();
  if (threadIdx.x == 0) {
    int acc = 0;
    for (int i = 0; i < nb; i++) { int t = s[i]; s[i] = acc; acc += t; }
  }
  __syncthreads();
  for (int i = threadIdx.x; i < nb; i += 256) bsum[i] = s[i];
}

__global__ __launch_bounds__(256) void scan_apply_kernel(
    const int* __restrict__ cnt, const int* __restrict__ bsum,
    int* __restrict__ offs, int* __restrict__ cursor, int n) {
  __shared__ int s[256];
  int b = blockIdx.x;
  int i = b * 256 + threadIdx.x;
  int v = (i < n) ? cnt[i] : 0;
  s[threadIdx.x] = v;
  __syncthreads();
  for (int d = 1; d < 256; d <<= 1) {
    int t = (threadIdx.x >= d) ? s[threadIdx.x - d] : 0;
    __syncthreads();
    s[threadIdx.x] += t;
    __syncthreads();
  }
  int excl = s[threadIdx.x] - v + bsum[b];
  if (i < n) { offs[i] = excl; cursor[i] = excl; }
  if (i == n - 1) offs[n] = excl + v;
}

__global__ void boundary_kernel(const int* __restrict__ batch, int* __restrict__ goff,
                                int n, int G) {
  int g = blockIdx.x * blockDim.x + threadIdx.x;
  if (g > G) return;
  int lo = 0, hi = n;
  while (lo < hi) {
    int mid = (lo + hi) >> 1;
    if (batch[mid] < g) lo = mid + 1; else hi = mid;
  }
  goff[g] = lo;
}

// ---------------- bond encoder (MFMA, LDS-free) ----------------
// Lane l computes t[k]=relu(attr·be1col_k) for its own A-frag slots
// (edge row = l&15, k = kt*32 + (l>>4)*8 + j), packs bf16, MFMA with
// prepped be2 frags, stores C (bf16) in dst-sorted order.
template <int DE>
__global__ __launch_bounds__(256) void bond_kernel(
    const float4* __restrict__ attr_s, const float* __restrict__ b1p,
    const unsigned short* __restrict__ be2f, unsigned short* __restrict__ ebond, int E) {
  constexpr int KT = (DE + 31) / 32;
  constexpr int NT = (DE + 15) / 16;
  constexpr int RB = KT * 32;
  int lane = threadIdx.x & 63;
  int nc = lane & 15, rr = (lane >> 4) * 4;
  int gw = (blockIdx.x * blockDim.x + threadIdx.x) >> 6;
  int nw = (gridDim.x * blockDim.x) >> 6;

  float b1v[3][KT * 8];
#pragma unroll
  for (int c = 0; c < 3; c++)
#pragma unroll
    for (int kk = 0; kk < KT * 8; kk++)
      b1v[c][kk] = b1p[lane * 48 + c * 16 + (kk >> 3) * 8 + (kk & 7)];

  short8v bfrag[NT][KT];
#pragma unroll
  for (int nt = 0; nt < NT; nt++)
#pragma unroll
    for (int kt = 0; kt < KT; kt++)
      bfrag[nt][kt] = *(const short8v*)(be2f + ((nt * KT + kt) * 64 + lane) * 8);

  int ntiles = (E + 15) >> 4;
  for (int tile = gw; tile < ntiles; tile += nw) {
    int j0 = tile << 4;
    int je = j0 + nc;  // edge row this lane's A-frag belongs to
    float4 a = attr_s[min(je, E - 1)];
    short8v af[KT];
#pragma unroll
    for (int kt = 0; kt < KT; kt++)
#pragma unroll
      for (int j = 0; j < 8; j++) {
        int kk = kt * 8 + j;
        float t = fmaxf(fmaf(a.x, b1v[0][kk], fmaf(a.y, b1v[1][kk], a.z * b1v[2][kk])), 0.f);
        af[kt][j] = (short)f2bf(t);
      }
    float4v acc[NT];
#pragma unroll
    for (int nt = 0; nt < NT; nt++) {
      acc[nt] = (float4v){0.f, 0.f, 0.f, 0.f};
#pragma unroll
      for (int kt = 0; kt < KT; kt++) acc[nt] = mfma16(af[kt], bfrag[nt][kt], acc[nt]);
    }
#pragma unroll
    for (int nt = 0; nt < NT; nt++)
#pragma unroll
      for (int r = 0; r < 4; r++) {
        int row = j0 + rr + r;
        if (row < E) ebond[(size_t)row * RB + nt * 16 + nc] = f2bf(acc[nt][r]);
      }
  }
}

// ---------------- edge aggregation (CSR gather, 8-wide batches) ----------------
template <int DH, int RB>
__global__ __launch_bounds__(256) void agg_kernel(
    const float* __restrict__ h, const unsigned short* __restrict__ eb,
    const float* __restrict__ epsp, const int* __restrict__ src_sorted,
    const int* __restrict__ offs, float* __restrict__ zout, int n_nodes) {
  int wid = (blockIdx.x * blockDim.x + threadIdx.x) >> 6;
  int nw = (gridDim.x * blockDim.x) >> 6;
  int lane = threadIdx.x & 63;
  float eps1 = 1.f + epsp[0];
  const bool hl = (DH == 64) || (lane < DH);
  const bool el = (RB == 64) || (lane < RB);
  for (int v = wid; v < n_nodes; v += nw) {
    float acc = hl ? eps1 * h[(size_t)v * DH + lane] : 0.f;
    int j = offs[v], e1 = offs[v + 1];
    for (; j + 8 <= e1; j += 8) {
      int ss[8];
      float eb8[8], hh[8];
#pragma unroll
      for (int q = 0; q < 8; q++) ss[q] = src_sorted[j + q];
#pragma unroll
      for (int q = 0; q < 8; q++)
        eb8[q] = el ? bf2f(eb[(size_t)(j + q) * RB + lane]) : 0.f;
#pragma unroll
      for (int q = 0; q < 8; q++) hh[q] = hl ? h[(size_t)ss[q] * DH + lane] : 0.f;
#pragma unroll
      for (int q = 0; q < 8; q++) acc += fmaxf(hh[q] + eb8[q], 0.f);
    }
    for (; j + 4 <= e1; j += 4) {
      int ss[4];
      float eb4[4], hh[4];
#pragma unroll
      for (int q = 0; q < 4; q++) ss[q] = src_sorted[j + q];
#pragma unroll
      for (int q = 0; q < 4; q++)
        eb4[q] = el ? bf2f(eb[(size_t)(j + q) * RB + lane]) : 0.f;
#pragma unroll
      for (int q = 0; q < 4; q++) hh[q] = hl ? h[(size_t)ss[q] * DH + lane] : 0.f;
#pragma unroll
      for (int q = 0; q < 4; q++) acc += fmaxf(hh[q] + eb4[q], 0.f);
    }
    for (; j < e1; j++) {
      int s = src_sorted[j];
      float b = el ? bf2f(eb[(size_t)j * RB + lane]) : 0.f;
      float hs = hl ? h[(size_t)s * DH + lane] : 0.f;
      acc += fmaxf(hs + b, 0.f);
    }
    if (el) zout[(size_t)v * RB + lane] = acc;
  }
}

// ---------------- node MLP + relu + BN (MFMA) ----------------
// A-frag for z read directly from global (rows affect only their own C rows,
// so tail clamping is safe). LDS only for the y (hidden) transpose.
template <int DIN>
__global__ __launch_bounds__(256) void node_mfma_kernel(
    const float* __restrict__ z, const unsigned short* __restrict__ m1f_g,
    const unsigned short* __restrict__ m2f_g, const float* __restrict__ bng,
    const float* __restrict__ bnb, const float* __restrict__ bnm,
    const float* __restrict__ bnv, float* __restrict__ xout, int n_nodes) {
  constexpr int KT = (DIN + 31) / 32;
  constexpr int NTH = (DIN + 15) / 16;
  constexpr int ZR = KT * 32;
  constexpr int LROW = 64 * 2 + 16;  // y rows always 64 cols bf16 + pad
  __shared__ __attribute__((aligned(16))) char lds_all[4 * 16 * LROW];
  char* yl = lds_all + (threadIdx.x >> 6) * (16 * LROW);
  int lane = threadIdx.x & 63;
  int nc = lane & 15, kg = lane >> 4, rr = kg * 4;
  int gw = (blockIdx.x * blockDim.x + threadIdx.x) >> 6;
  int nw = (gridDim.x * blockDim.x) >> 6;

  short8v m1f[NTH][KT], m2f[4][KT];
#pragma unroll
  for (int nt = 0; nt < NTH; nt++)
#pragma unroll
    for (int kt = 0; kt < KT; kt++)
      m1f[nt][kt] = *(const short8v*)(m1f_g + ((nt * KT + kt) * 64 + lane) * 8);
#pragma unroll
  for (int nt = 0; nt < 4; nt++)
#pragma unroll
    for (int kt = 0; kt < KT; kt++)
      m2f[nt][kt] = *(const short8v*)(m2f_g + ((nt * KT + kt) * 64 + lane) * 8);

  float scv[4], shv[4];
#pragma unroll
  for (int nt = 0; nt < 4; nt++) {
    int f = nt * 16 + nc;
    float sc = bng[f] * rsqrtf(bnv[f] + 1e-5f);
    scv[nt] = sc;
    shv[nt] = bnb[f] - bnm[f] * sc;
  }

  int ntiles = (n_nodes + 15) >> 4;
  for (int tile = gw; tile < ntiles; tile += nw) {
    int v0 = tile << 4;
    int vr = min(v0 + nc, n_nodes - 1);  // A row this lane reads
    short8v af[KT];
#pragma unroll
    for (int kt = 0; kt < KT; kt++) {
      const float* zp = z + (size_t)vr * ZR + kt * 32 + kg * 8;
      float4 z0 = *(const float4*)(zp);
      float4 z1 = *(const float4*)(zp + 4);
      af[kt][0] = (short)f2bf(z0.x); af[kt][1] = (short)f2bf(z0.y);
      af[kt][2] = (short)f2bf(z0.z); af[kt][3] = (short)f2bf(z0.w);
      af[kt][4] = (short)f2bf(z1.x); af[kt][5] = (short)f2bf(z1.y);
      af[kt][6] = (short)f2bf(z1.z); af[kt][7] = (short)f2bf(z1.w);
    }
    float4v acch[NTH];
#pragma unroll
    for (int nt = 0; nt < NTH; nt++) {
      acch[nt] = (float4v){0.f, 0.f, 0.f, 0.f};
#pragma unroll
      for (int kt = 0; kt < KT; kt++) acch[nt] = mfma16(af[kt], m1f[nt][kt], acch[nt]);
    }
    // y = relu(.) -> LDS transpose (C-layout row rr+r, col nt*16+nc)
#pragma unroll
    for (int nt = 0; nt < NTH; nt++)
#pragma unroll
      for (int r = 0; r < 4; r++)
        *(unsigned short*)(yl + (rr + r) * LROW + (nt * 16 + nc) * 2) =
            f2bf(fmaxf(acch[nt][r], 0.f));
    asm volatile("" ::: "memory");
    short8v af2[KT];
#pragma unroll
    for (int kt = 0; kt < KT; kt++)
      af2[kt] = *(const short8v*)(yl + nc * LROW + kg * 16 + kt * 64);
    float4v acco[4];
#pragma unroll
    for (int nt = 0; nt < 4; nt++) {
      acco[nt] = (float4v){0.f, 0.f, 0.f, 0.f};
#pragma unroll
      for (int kt = 0; kt < KT; kt++) acco[nt] = mfma16(af2[kt], m2f[nt][kt], acco[nt]);
    }
#pragma unroll
    for (int nt = 0; nt < 4; nt++)
#pragma unroll
      for (int r = 0; r < 4; r++) {
        int v = v0 + rr + r;
        if (v < n_nodes)
          xout[(size_t)v * 64 + nt * 16 + nc] =
              fmaf(fmaxf(acco[nt][r], 0.f), scv[nt], shv[nt]);
      }
    asm volatile("" ::: "memory");
  }
}

// ---------------- graph mean-pool of concat(x1..x4) ----------------
__global__ __launch_bounds__(256) void pool_kernel(
    const float* __restrict__ x1, const float* __restrict__ x2,
    const float* __restrict__ x3, const float* __restrict__ x4,
    const int* __restrict__ goff, float* __restrict__ pooled, int G) {
  int g = blockIdx.x;
  int c = threadIdx.x;
  int sel = c >> 6, f = c & 63;
  const float* x = (sel == 0) ? x1 : (sel == 1) ? x2 : (sel == 2) ? x3 : x4;
  int s = goff[g], e = goff[g + 1];
  float acc = 0.f;
  for (int v = s; v < e; v++) acc += x[(size_t)v * 64 + f];
  float cnt = (float)(e - s);
  pooled[g * 256 + c] = acc / fmaxf(cnt, 1.0f);
}

// ---------------- FC head ----------------
__global__ __launch_bounds__(64) void head_kernel(
    const float* __restrict__ pooled,
    const float* __restrict__ w1, const float* __restrict__ b1,
    const float* __restrict__ w2, const float* __restrict__ b2,
    const float* __restrict__ w3, const float* __restrict__ b3,
    const float* __restrict__ w4, const float* __restrict__ b4,
    float* __restrict__ out, int G) {
  int g = blockIdx.x;
  int lane = threadIdx.x;
  __shared__ float sh[256];
  for (int i = lane; i < 256; i += 64) sh[i] = pooled[g * 256 + i];
  __syncthreads();
  float h1 = b1[lane];
#pragma unroll 8
  for (int i = 0; i < 256; i++) h1 = fmaf(sh[i], w1[i * 64 + lane], h1);
  h1 = fmaxf(h1, 0.f);
  __syncthreads();
  sh[lane] = h1;
  __syncthreads();
  float h2 = b2[lane];
#pragma unroll
  for (int i = 0; i < 64; i++) h2 = fmaf(sh[i], w2[i * 64 + lane], h2);
  h2 = fmaxf(h2, 0.f);
  __syncthreads();
  sh[lane] = h2;
  __syncthreads();
  float h3 = b3[lane];
#pragma unroll
  for (int i = 0; i < 64; i++) h3 = fmaf(sh[i], w3[i * 64 + lane], h3);
  h3 = fmaxf(h3, 0.f);
  float p = h3 * w4[lane];
  for (int d = 32; d > 0; d >>= 1) p += __shfl_down(p, d);
  if (lane == 0) out[g] = p + b4[0];
}

// ---------------------------------------------------------------------------

extern "C" void kernel_launch(void* const* d_in, const int* in_sizes, int n_in,
                              void* d_out, int out_size, void* d_ws, size_t ws_size,
                              hipStream_t stream) {
  const float* x      = (const float*)d_in[0];
  const float* eattr  = (const float*)d_in[1];
  const float* c1_be1 = (const float*)d_in[2];
  const float* c1_be2 = (const float*)d_in[3];
  const float* c1_m1  = (const float*)d_in[4];
  const float* c1_m2  = (const float*)d_in[5];
  const float* c1_eps = (const float*)d_in[6];
  const float* c2_be1 = (const float*)d_in[7];
  const float* c2_be2 = (const float*)d_in[8];
  const float* c2_m1  = (const float*)d_in[9];
  const float* c2_m2  = (const float*)d_in[10];
  const float* c2_eps = (const float*)d_in[11];
  const float* c3_be1 = (const float*)d_in[12];
  const float* c3_be2 = (const float*)d_in[13];
  const float* c3_m1  = (const float*)d_in[14];
  const float* c3_m2  = (const float*)d_in[15];
  const float* c3_eps = (const float*)d_in[16];
  const float* bn_g[4] = {(const float*)d_in[17], (const float*)d_in[21],
                          (const float*)d_in[25], (const float*)d_in[29]};
  const float* bn_b[4] = {(const float*)d_in[18], (const float*)d_in[22],
                          (const float*)d_in[26], (const float*)d_in[30]};
  const float* bn_m[4] = {(const float*)d_in[19], (const float*)d_in[23],
                          (const float*)d_in[27], (const float*)d_in[31]};
  const float* bn_v[4] = {(const float*)d_in[20], (const float*)d_in[24],
                          (const float*)d_in[28], (const float*)d_in[32]};
  const float* fc1_w = (const float*)d_in[33];
  const float* fc1_b = (const float*)d_in[34];
  const float* fc2_w = (const float*)d_in[35];
  const float* fc2_b = (const float*)d_in[36];
  const float* fc3_w = (const float*)d_in[37];
  const float* fc3_b = (const float*)d_in[38];
  const float* fc4_w = (const float*)d_in[39];
  const float* fc4_b = (const float*)d_in[40];
  const int* eidx  = (const int*)d_in[41];
  const int* batch = (const int*)d_in[42];

  const int N = in_sizes[0] / 28;
  const int E = in_sizes[1] / 3;
  const int G = out_size;
  const int* src = eidx;
  const int* dst = eidx + E;
  float* outf = (float*)d_out;

  char* p = (char*)d_ws;
  auto alloc = [&](size_t bytes) {
    char* r = p;
    p += (bytes + 255) & ~(size_t)255;
    return r;
  };
  const int NBLK = (N + 255) / 256;
  int* counts   = (int*)alloc((size_t)N * 4);
  int* offs     = (int*)alloc((size_t)(N + 1) * 4);
  int* cursor   = (int*)alloc((size_t)N * 4);
  int* bsum     = (int*)alloc((size_t)NBLK * 4);
  int* goff     = (int*)alloc((size_t)(G + 1) * 4);
  int* src_s    = (int*)alloc((size_t)E * 4);
  float4* attr_s = (float4*)alloc((size_t)E * 16);
  unsigned short* FB = (unsigned short*)alloc(9 * 4096 * 2);   // frag weights
  float* B1P    = (float*)alloc(3 * 64 * 48 * 4);              // be1 lane tables
  unsigned short* ebond = (unsigned short*)alloc((size_t)E * 64 * 2);
  float* zbuf   = (float*)alloc((size_t)N * 64 * 4);
  float* x1     = (float*)alloc((size_t)N * 64 * 4);
  float* x2     = (float*)alloc((size_t)N * 64 * 4);
  float* x3     = (float*)alloc((size_t)N * 64 * 4);
  float* x4     = (float*)alloc((size_t)N * 64 * 4);
  float* pooled = (float*)alloc((size_t)G * 256 * 4);
  (void)ws_size; (void)n_in;

  prep_kernel<<<12, 256, 0, stream>>>(c1_be2, c2_be2, c3_be2, c1_m1, c2_m1, c3_m1,
                                      c1_m2, c2_m2, c3_m2, c1_be1, c2_be1, c3_be1,
                                      FB, B1P);
  hipMemsetAsync(counts, 0, (size_t)N * 4, stream);
  hist_kernel<<<1024, 256, 0, stream>>>(dst, counts, E);
  boundary_kernel<<<(G + 128) / 128, 128, 0, stream>>>(batch, goff, N, G);
  block_reduce_kernel<<<NBLK, 256, 0, stream>>>(counts, bsum, N);
  bsum_scan_kernel<<<1, 256, 0, stream>>>(bsum, NBLK);
  scan_apply_kernel<<<NBLK, 256, 0, stream>>>(counts, bsum, offs, cursor, N);
  fill_perm_kernel<<<1024, 256, 0, stream>>>(src, dst, eattr, cursor, src_s, attr_s, E);

  unsigned short* FB_be2[3] = {FB + 0 * 4096, FB + 1 * 4096, FB + 2 * 4096};
  unsigned short* FB_m1[3]  = {FB + 3 * 4096, FB + 4 * 4096, FB + 5 * 4096};
  unsigned short* FB_m2[3]  = {FB + 6 * 4096, FB + 7 * 4096, FB + 8 * 4096};
  float* B1[3] = {B1P, B1P + 64 * 48, B1P + 2 * 64 * 48};

  dim3 blk(256);
  // layer 1
  bond_kernel<28><<<1024, blk, 0, stream>>>(attr_s, B1[0], FB_be2[0], ebond, E);
  agg_kernel<28, 32><<<2048, blk, 0, stream>>>(x, ebond, c1_eps, src_s, offs, zbuf, N);
  node_mfma_kernel<28><<<512, blk, 0, stream>>>(zbuf, FB_m1[0], FB_m2[0], bn_g[0],
                                                bn_b[0], bn_m[0], bn_v[0], x1, N);
  // layer 2
  bond_kernel<64><<<1024, blk, 0, stream>>>(attr_s, B1[1], FB_be2[1], ebond, E);
  agg_kernel<64, 64><<<2048, blk, 0, stream>>>(x1, ebond, c2_eps, src_s, offs, zbuf, N);
  node_mfma_kernel<64><<<512, blk, 0, stream>>>(zbuf, FB_m1[1], FB_m2[1], bn_g[1],
                                                bn_b[1], bn_m[1], bn_v[1], x2, N);
  // layer 3
  bond_kernel<64><<<1024, blk, 0, stream>>>(attr_s, B1[2], FB_be2[2], ebond, E);
  agg_kernel<64, 64><<<2048, blk, 0, stream>>>(x2, ebond, c3_eps, src_s, offs, zbuf, N);
  node_mfma_kernel<64><<<512, blk, 0, stream>>>(zbuf, FB_m1[2], FB_m2[2], bn_g[2],
                                                bn_b[2], bn_m[2], bn_v[2], x3, N);
  // layer 4 (conv3 weights reused -> ebond already holds c3 bond encodings)
  agg_kernel<64, 64><<<2048, blk, 0, stream>>>(x3, ebond, c3_eps, src_s, offs, zbuf, N);
  node_mfma_kernel<64><<<512, blk, 0, stream>>>(zbuf, FB_m1[2], FB_m2[2], bn_g[3],
                                                bn_b[3], bn_m[3], bn_v[3], x4, N);

  pool_kernel<<<G, blk, 0, stream>>>(x1, x2, x3, x4, goff, pooled, G);
  head_kernel<<<G, 64, 0, stream>>>(pooled, fc1_w, fc1_b, fc2_w, fc2_b, fc3_w,
                                    fc3_b, fc4_w, fc4_b, outf, G);
}